// Round 1
// 79.828 us; speedup vs baseline: 1.0128x; 1.0128x over previous
//
#include <hip/hip_runtime.h>
#include <stdint.h>

#define N_TOK 16384
#define F_DIM 128
#define U_DIM 64
#define E_DIM 32

typedef __bf16 bf16x8 __attribute__((ext_vector_type(8)));
typedef float  floatx4 __attribute__((ext_vector_type(4)));

#define MFMA16(a, b, c) __builtin_amdgcn_mfma_f32_16x16x32_bf16((a), (b), (c), 0, 0, 0)

__device__ __forceinline__ unsigned short f2bf(float f) {
  union { float f; unsigned u; } v; v.f = f;
  unsigned r = v.u + 0x7FFFu + ((v.u >> 16) & 1u);  // RNE
  return (unsigned short)(r >> 16);
}

// ---------------------------------------------------------------------------
// Prep: fragment-linear bf16 weights in ws. Coalesced reads (u == lane is the
// fastest dim of We) and 16B coalesced stores.
//  wsWe elem idx: ((e*4+ks)*4+quad)*512 + u*8 + j   == We[e][ks*32+quad*8+j][u]
//  wsWg elem idx: ((et*4+ks)*64 + lane)*8 + j       == Wg[ks*32+(lane>>4)*8+j][et*16+(lane&15)]
// ---------------------------------------------------------------------------
__global__ __launch_bounds__(256) void moe_prep(
    const float* __restrict__ Wg, const float* __restrict__ We,
    unsigned short* __restrict__ wsWe, unsigned short* __restrict__ wsWg) {
  int t = blockIdx.x * 256 + threadIdx.x;
  if (t < 32768) {
    int u = t & 63, quad = (t >> 6) & 3, ks = (t >> 8) & 3, e = t >> 10;
    int f0 = ks * 32 + quad * 8;
    const float* src = We + e * 8192 + f0 * 64 + u;  // wave reads full 256B rows
    union { unsigned short us[8]; uint4 q; } p;
#pragma unroll
    for (int j = 0; j < 8; j++) p.us[j] = f2bf(src[j * 64]);
    *(uint4*)(wsWe + t * 8) = p.q;
  } else if (t < 32768 + 512) {
    int t2 = t - 32768;
    int l15 = t2 & 15, quad = (t2 >> 4) & 3, ks = (t2 >> 6) & 3, et = t2 >> 8;
    int e = et * 16 + l15, f0 = ks * 32 + quad * 8;
    union { unsigned short us[8]; uint4 q; } p;
#pragma unroll
    for (int j = 0; j < 8; j++) p.us[j] = f2bf(Wg[(f0 + j) * 32 + e]);
    *(uint4*)(wsWg + t2 * 8) = p.q;
  }
}

// ---------------------------------------------------------------------------
// Main: 256 wgs x 512 thr (8 waves, 2/SIMD — occupancy fix). Wave tile
// 32m x 16u: wr = wid>>2 picks row half, wc = wid&3 picks u-quarter.
// Two waves per SIMD let one wave's epilogue VALU + prefetch issue overlap
// the other's MFMA block (at 1 wave/SIMD that bubble was exposed matrix-pipe
// idle). B streamed from L2 via depth-4 register ring (prefetch e+3).
// Gate rows read as float4 from LDS, double-buffered one expert ahead.
// 2 barriers total.
// ---------------------------------------------------------------------------
__global__ __launch_bounds__(512, 2) void moe_main(
    const float* __restrict__ x,
    const float* __restrict__ bg,
    const float* __restrict__ be,
    const unsigned short* __restrict__ wsWe,
    const unsigned short* __restrict__ wsWg,
    float* __restrict__ out) {
  __shared__ unsigned short Xs[64 * 136];  // padded rows
  __shared__ float Gs[E_DIM][68];          // gate [e][row], padded

  const int tid  = threadIdx.x;
  const int lane = tid & 63;
  const int wid  = tid >> 6;       // 0..7
  const int quad = lane >> 4;
  const int l15  = lane & 15;
  const int wr   = wid >> 2;       // 0..1  row half
  const int wc   = wid & 3;        // 0..3  u quarter
  const int u    = wc * 16 + l15;
  const int base = blockIdx.x * 64;

  // ---- B ring: prefetch experts 0..2 (L2) before anything else
  bf16x8 bbuf[4][4];
  float bevb[4];
#pragma unroll
  for (int e0 = 0; e0 < 3; e0++) {
#pragma unroll
    for (int ks = 0; ks < 4; ks++)
      bbuf[e0][ks] = *(const bf16x8*)(wsWe + (size_t)((e0 * 4 + ks) * 4 + quad) * 512 + u * 8);
    bevb[e0] = be[e0 * U_DIM + u];
  }

  // ---- stage X tile (fp32 -> bf16) into LDS: 512 thr x 16 floats = 64x128
  {
    const int row = tid >> 3;
    const int c16 = tid & 7;
    const float4* src = (const float4*)(x + (size_t)(base + row) * F_DIM + c16 * 16);
    float4 v0 = src[0], v1 = src[1], v2 = src[2], v3 = src[3];
    union { unsigned short us[16]; uint4 q[2]; } pk;
    pk.us[0]  = f2bf(v0.x); pk.us[1]  = f2bf(v0.y); pk.us[2]  = f2bf(v0.z); pk.us[3]  = f2bf(v0.w);
    pk.us[4]  = f2bf(v1.x); pk.us[5]  = f2bf(v1.y); pk.us[6]  = f2bf(v1.z); pk.us[7]  = f2bf(v1.w);
    pk.us[8]  = f2bf(v2.x); pk.us[9]  = f2bf(v2.y); pk.us[10] = f2bf(v2.z); pk.us[11] = f2bf(v2.w);
    pk.us[12] = f2bf(v3.x); pk.us[13] = f2bf(v3.y); pk.us[14] = f2bf(v3.z); pk.us[15] = f2bf(v3.w);
    uint4* dst = (uint4*)&Xs[row * 136 + c16 * 16];
    dst[0] = pk.q[0];
    dst[1] = pk.q[1];
  }
  __syncthreads();  // barrier 1: X ready

  // ---- gate: 8 waves, wave = (rowgroup rg, expert-half et)
  {
    const int rg = wid >> 1;   // 0..3 -> rows rg*16..
    const int et = wid & 1;    // 0..1 -> experts et*16..
    bf16x8 ag[4];
#pragma unroll
    for (int ks = 0; ks < 4; ks++)
      ag[ks] = *(const bf16x8*)&Xs[(rg * 16 + l15) * 136 + ks * 32 + quad * 8];
    floatx4 g = {0.f, 0.f, 0.f, 0.f};
#pragma unroll
    for (int ks = 0; ks < 4; ks++) {
      bf16x8 wb = *(const bf16x8*)(wsWg + (size_t)((et * 4 + ks) * 64 + lane) * 8);
      g = MFMA16(ag[ks], wb, g);
    }
    float bgv = bg[et * 16 + l15];
#pragma unroll
    for (int r = 0; r < 4; r++)
      Gs[et * 16 + l15][rg * 16 + quad * 4 + r] = g[r] + bgv;
  }

  // ---- preload this wave's A fragments (32 rows; X never re-read after)
  bf16x8 a[2][4];
#pragma unroll
  for (int mb = 0; mb < 2; mb++)
#pragma unroll
    for (int ks = 0; ks < 4; ks++)
      a[mb][ks] = *(const bf16x8*)&Xs[(wr * 32 + mb * 16 + l15) * 136 + ks * 32 + quad * 8];
  __syncthreads();  // barrier 2: Gs ready (last barrier)

  float oacc[8];
#pragma unroll
  for (int i = 0; i < 8; i++) oacc[i] = 0.f;

  // ---- gate double-buffer: preload e=0 as float4 rows
  float4 gbuf[2][2];
#pragma unroll
  for (int mb = 0; mb < 2; mb++)
    gbuf[0][mb] = *(const float4*)&Gs[0][wr * 32 + mb * 16 + quad * 4];

  // ---- expert loop: no barriers
#pragma unroll 4
  for (int e = 0; e < E_DIM; ++e) {
    const int c = e & 3;
    const int gp = e & 1;

    // prefetch B for e+3 into the slot last used by e-1 (consumed)
    if (e + 3 < E_DIM) {
#pragma unroll
      for (int ks = 0; ks < 4; ks++)
        bbuf[(e + 3) & 3][ks] =
            *(const bf16x8*)(wsWe + (size_t)(((e + 3) * 4 + ks) * 4 + quad) * 512 + u * 8);
      bevb[(e + 3) & 3] = be[(e + 3) * U_DIM + u];
    }
    // prefetch gate rows for e+1 (hidden under e's MFMAs)
    if (e + 1 < E_DIM) {
#pragma unroll
      for (int mb = 0; mb < 2; mb++)
        gbuf[gp ^ 1][mb] = *(const float4*)&Gs[e + 1][wr * 32 + mb * 16 + quad * 4];
    }

    const float bev = bevb[c];
    floatx4 h[2];
#pragma unroll
    for (int mb = 0; mb < 2; mb++) h[mb] = {bev, bev, bev, bev};
#pragma unroll
    for (int ks = 0; ks < 4; ks++)
#pragma unroll
      for (int mb = 0; mb < 2; mb++)
        h[mb] = MFMA16(a[mb][ks], bbuf[c][ks], h[mb]);

    // epilogue: out += gate * leaky(h),  leaky(t) = max(t, 0.01t)
#pragma unroll
    for (int mb = 0; mb < 2; mb++) {
      const float4 g4 = gbuf[gp][mb];
      const float gr[4] = {g4.x, g4.y, g4.z, g4.w};
#pragma unroll
      for (int r = 0; r < 4; r++) {
        float t = h[mb][r];
        t = fmaxf(t, 0.01f * t);
        oacc[mb * 4 + r] = fmaf(gr[r], t, oacc[mb * 4 + r]);
      }
    }
  }

  // ---- store
#pragma unroll
  for (int mb = 0; mb < 2; mb++)
#pragma unroll
    for (int r = 0; r < 4; r++)
      out[(size_t)(base + wr * 32 + mb * 16 + quad * 4 + r) * U_DIM + u] = oacc[mb * 4 + r];
}

extern "C" void kernel_launch(void* const* d_in, const int* in_sizes, int n_in,
                              void* d_out, int out_size, void* d_ws, size_t ws_size,
                              hipStream_t stream) {
  const float* x  = (const float*)d_in[0];
  const float* Wg = (const float*)d_in[1];
  const float* bg = (const float*)d_in[2];
  const float* We = (const float*)d_in[3];
  const float* be = (const float*)d_in[4];
  unsigned short* wsWe = (unsigned short*)d_ws;              // 512 KB
  unsigned short* wsWg = wsWe + E_DIM * U_DIM * F_DIM;       // +8 KB
  (void)in_sizes; (void)n_in; (void)out_size; (void)ws_size;

  moe_prep<<<130, 256, 0, stream>>>(Wg, We, wsWe, wsWg);
  moe_main<<<N_TOK / 64, 512, 0, stream>>>(x, bg, be, wsWe, wsWg, (float*)d_out);
}